// Round 10
// baseline (320.540 us; speedup 1.0000x reference)
//
#include <hip/hip_runtime.h>
#include <cstdint>

typedef unsigned short ushort_t;
typedef __attribute__((ext_vector_type(8))) __bf16 bf16x8;
typedef __attribute__((ext_vector_type(4))) float f32x4;
typedef __attribute__((ext_vector_type(4))) int i32x4;

#define NG 128
#define NP 32
#define NH 64
#define ND1 512
#define ND2 1024

__device__ inline ushort_t f2bf(float f) {
    uint32_t u = __float_as_uint(f);
    uint32_t r = (u + 0x7FFFu + ((u >> 16) & 1u)) >> 16;
    return (ushort_t)r;
}

#define GLL16(gp, lp) __builtin_amdgcn_global_load_lds( \
    (const __attribute__((address_space(1))) unsigned int*)(gp), \
    (__attribute__((address_space(3))) unsigned int*)(lp), 16, 0, 0)

// ---------------------------------------------------------------------------
// K2_fused: grid 384.
//  blocks 0..255 (g,half): zero psum/psq + inline weight-fold + BN1 analytics,
//    then DIRECTLY materialize h1[g*1024 + i*32 + j][ch] = relu(uj[j]-wi[i])
//    as bf16 in the k3 swizzled layout (16B chunk c of each 128B window at
//    c^(row&7)), via a 32KB LDS stage per 64-row i-block.
//  blocks 256..383: W2 [512,1024] fp32 -> W2T bf16 [1024][512], same swizzle.
// u1/w1 are never written in this path.
// ---------------------------------------------------------------------------
__global__ void k2_fused(const float* __restrict__ hstates, const float* __restrict__ pos,
                         const float* __restrict__ spd, const float* __restrict__ W1,
                         const float* __restrict__ g1, const float* __restrict__ be1,
                         const float* __restrict__ Ws, const float* __restrict__ bs,
                         const float* __restrict__ Wv, const float* __restrict__ bv,
                         const float* __restrict__ b1, const float* __restrict__ W2,
                         ushort_t* __restrict__ W2T, ushort_t* __restrict__ h1,
                         float* __restrict__ psum) {
    __shared__ float hid_s[32][64];
    __shared__ float pos_s[32][2];
    __shared__ float spd_s[32];
    __shared__ ushort_t tile[64][65];
    __shared__ __align__(16) char stage[32768];
    int b = blockIdx.x, tid = threadIdx.x;
    if (b < 256) {
        // zero psum+psq (contiguous 262144 floats)
        int t0 = b * 256 + tid;
        #pragma unroll
        for (int z = 0; z < 4; z++) psum[t0 + z * 65536] = 0.f;
        int g = b >> 1, half = b & 1;
        int ch = (half << 8) + tid;
        for (int t = tid; t < 2048; t += 256) hid_s[t >> 6][t & 63] = hstates[g * 2048 + t];
        if (tid < 64) pos_s[tid >> 1][tid & 1] = pos[g * 64 + tid];
        if (tid < 32) spd_s[tid] = spd[g * 32 + tid];
        // inline weight fold
        float m0 = 0.f, m1 = 0.f, uu = 0.f, vv = b1[ch];
        for (int e = 0; e < 64; e++) {
            float w1a = W1[e * ND1 + ch];
            float w1c = W1[(128 + e) * ND1 + ch];
            m0 += Ws[e] * w1a;
            m1 += Ws[64 + e] * w1a;
            uu += Wv[e] * w1c;
            vv += bs[e] * w1a + bv[e] * w1c;
        }
        __syncthreads();
        float cj[32], qj[32];
        #pragma unroll
        for (int j = 0; j < 32; j++) {
            qj[j] = pos_s[j][0] * m0 + pos_s[j][1] * m1;
            cj[j] = vv + spd_s[j] * uu;
        }
        for (int h = 0; h < 64; h++) {
            float w = W1[(64 + h) * ND1 + ch];
            #pragma unroll
            for (int j = 0; j < 32; j++) cj[j] += hid_s[j][h] * w;
        }
        float S1 = 0.f, S2 = 0.f, C1 = 0.f, Cq = 0.f, C2 = 0.f;
        #pragma unroll
        for (int j = 0; j < 32; j++) {
            S1 += qj[j]; S2 += qj[j] * qj[j];
            C1 += cj[j]; Cq += cj[j] * qj[j]; C2 += cj[j] * cj[j];
        }
        float mean = C1 * (1.0f / 32.0f);
        float sumsq = 64.f * S2 - 2.f * S1 * S1 + 64.f * Cq - 2.f * S1 * C1 + 32.f * C2;
        float var = sumsq * (1.0f / 1024.0f) - mean * mean;
        float A1 = rsqrtf(var + 1e-5f) * g1[ch];
        float B1 = be1[ch] - mean * A1;
        // uj/wi in registers
        float uj[32], wi[32];
        #pragma unroll
        for (int j = 0; j < 32; j++) {
            uj[j] = (qj[j] + cj[j]) * A1 + B1;
            wi[j] = qj[j] * A1;
        }
        // h1 emission: 16 i-blocks of 64 rows (2 i-values x 32 j)
        int wloc = (ch >> 6) & 3;       // 128B window within this 512B half-row
        int chsw = (ch >> 3) & 7;       // 16B chunk within window
        int chlo = (ch & 7) * 2;        // byte within chunk
        char* sbase = stage + wloc * 128 + chlo;
        #pragma unroll
        for (int ib = 0; ib < 16; ib++) {
            __syncthreads();            // stage free (prev drain done)
            #pragma unroll
            for (int ii = 0; ii < 2; ii++) {
                float w = wi[ib * 2 + ii];
                #pragma unroll
                for (int j = 0; j < 32; j++) {
                    float v = fmaxf(uj[j] - w, 0.f);
                    *(ushort_t*)(sbase + (ii * 32 + j) * 512 + ((chsw ^ (j & 7)) << 4)) = f2bf(v);
                }
            }
            __syncthreads();
            // drain: LDS mirrors global layout -> linear copy; coalesced 16B stores
            int r = tid >> 2, seg = tid & 3;
            char* gdst = (char*)h1 + (size_t)(g * 1024 + ib * 64 + r) * 1024 + half * 512 + seg * 128;
            const char* lsrc = stage + r * 512 + seg * 128;
            #pragma unroll
            for (int q = 0; q < 8; q++) {
                int c = ((q ^ (r & 7)) << 4);   // spread chunks across banks
                *reinterpret_cast<i32x4*>(gdst + c) = *reinterpret_cast<const i32x4*>(lsrc + c);
            }
        }
    } else {
        // W2T transpose with swizzled chunk layout
        int tb = b - 256;
        int kb2 = tb & 7, nb = tb >> 3;
        #pragma unroll
        for (int e = 0; e < 16; e++) {
            int lin = tid + e * 256;
            int k = lin >> 6, n = lin & 63;
            tile[k][n] = f2bf(W2[(kb2 * 64 + k) * ND2 + nb * 64 + n]);
        }
        __syncthreads();
        #pragma unroll
        for (int e = 0; e < 16; e++) {
            int lin = tid + e * 256;
            int kl = lin & 63, nl = lin >> 6;
            int n = nb * 64 + nl, k = kb2 * 64 + kl;
            int idx = n * ND1 + ((k >> 6) << 6) + (((((k >> 3) & 7) ^ (n & 7))) << 3) + (k & 7);
            W2T[idx] = tile[kl][nl];
        }
    }
}

// ---------------------------------------------------------------------------
// Fallback path kernels (ws too small for full h1): identical to R7.
// ---------------------------------------------------------------------------
__global__ void k2_all(const float* __restrict__ hstates, const float* __restrict__ pos,
                       const float* __restrict__ spd, const float* __restrict__ W1,
                       const float* __restrict__ g1, const float* __restrict__ be1,
                       const float* __restrict__ Ws, const float* __restrict__ bs,
                       const float* __restrict__ Wv, const float* __restrict__ bv,
                       const float* __restrict__ b1, const float* __restrict__ W2,
                       ushort_t* __restrict__ W2T,
                       float* __restrict__ u1, float* __restrict__ w1,
                       float* __restrict__ psum) {
    __shared__ float hid_s[32][64];
    __shared__ float pos_s[32][2];
    __shared__ float spd_s[32];
    __shared__ ushort_t tile[64][65];
    int b = blockIdx.x, tid = threadIdx.x;
    if (b < 256) {
        int t0 = b * 256 + tid;
        #pragma unroll
        for (int z = 0; z < 4; z++) psum[t0 + z * 65536] = 0.f;
        int g = b >> 1;
        int ch = ((b & 1) << 8) + tid;
        for (int t = tid; t < 2048; t += 256) hid_s[t >> 6][t & 63] = hstates[g * 2048 + t];
        if (tid < 64) pos_s[tid >> 1][tid & 1] = pos[g * 64 + tid];
        if (tid < 32) spd_s[tid] = spd[g * 32 + tid];
        float m0 = 0.f, m1 = 0.f, uu = 0.f, vv = b1[ch];
        for (int e = 0; e < 64; e++) {
            float w1a = W1[e * ND1 + ch];
            float w1c = W1[(128 + e) * ND1 + ch];
            m0 += Ws[e] * w1a;
            m1 += Ws[64 + e] * w1a;
            uu += Wv[e] * w1c;
            vv += bs[e] * w1a + bv[e] * w1c;
        }
        __syncthreads();
        float cj[32], qj[32];
        #pragma unroll
        for (int j = 0; j < 32; j++) {
            qj[j] = pos_s[j][0] * m0 + pos_s[j][1] * m1;
            cj[j] = vv + spd_s[j] * uu;
        }
        for (int h = 0; h < 64; h++) {
            float w = W1[(64 + h) * ND1 + ch];
            #pragma unroll
            for (int j = 0; j < 32; j++) cj[j] += hid_s[j][h] * w;
        }
        float S1 = 0.f, S2 = 0.f, C1 = 0.f, Cq = 0.f, C2 = 0.f;
        #pragma unroll
        for (int j = 0; j < 32; j++) {
            S1 += qj[j]; S2 += qj[j] * qj[j];
            C1 += cj[j]; Cq += cj[j] * qj[j]; C2 += cj[j] * cj[j];
        }
        float mean = C1 * (1.0f / 32.0f);
        float sumsq = 64.f * S2 - 2.f * S1 * S1 + 64.f * Cq - 2.f * S1 * C1 + 32.f * C2;
        float var = sumsq * (1.0f / 1024.0f) - mean * mean;
        float A1 = rsqrtf(var + 1e-5f) * g1[ch];
        float B1 = be1[ch] - mean * A1;
        #pragma unroll
        for (int j = 0; j < 32; j++) {
            u1[(g * 32 + j) * ND1 + ch] = (qj[j] + cj[j]) * A1 + B1;
            w1[(g * 32 + j) * ND1 + ch] = qj[j] * A1;
        }
    } else {
        int tb = b - 256;
        int kb2 = tb & 7, nb = tb >> 3;
        #pragma unroll
        for (int e = 0; e < 16; e++) {
            int lin = tid + e * 256;
            int k = lin >> 6, n = lin & 63;
            tile[k][n] = f2bf(W2[(kb2 * 64 + k) * ND2 + nb * 64 + n]);
        }
        __syncthreads();
        #pragma unroll
        for (int e = 0; e < 16; e++) {
            int lin = tid + e * 256;
            int kl = lin & 63, nl = lin >> 6;
            int n = nb * 64 + nl, k = kb2 * 64 + kl;
            int idx = n * ND1 + ((k >> 6) << 6) + (((((k >> 3) & 7) ^ (n & 7))) << 3) + (k & 7);
            W2T[idx] = tile[kl][nl];
        }
    }
}

__global__ void k2b_h1(const float* __restrict__ u1c, const float* __restrict__ w1c,
                       ushort_t* __restrict__ h1) {
    int t = blockIdx.x * 256 + threadIdx.x;
    int k8 = t & 63;
    int row = t >> 6;
    int gc = row >> 10, rem = row & 1023;
    int i = rem >> 5, j = rem & 31;
    const float4* pu = reinterpret_cast<const float4*>(u1c + (size_t)(gc * 32 + j) * ND1 + k8 * 8);
    const float4* pw = reinterpret_cast<const float4*>(w1c + (size_t)(gc * 32 + i) * ND1 + k8 * 8);
    float4 ua = pu[0], ub = pu[1], wa = pw[0], wb = pw[1];
    uint32_t p0 = (uint32_t)f2bf(fmaxf(ua.x - wa.x, 0.f)) | ((uint32_t)f2bf(fmaxf(ua.y - wa.y, 0.f)) << 16);
    uint32_t p1 = (uint32_t)f2bf(fmaxf(ua.z - wa.z, 0.f)) | ((uint32_t)f2bf(fmaxf(ua.w - wa.w, 0.f)) << 16);
    uint32_t p2 = (uint32_t)f2bf(fmaxf(ub.x - wb.x, 0.f)) | ((uint32_t)f2bf(fmaxf(ub.y - wb.y, 0.f)) << 16);
    uint32_t p3 = (uint32_t)f2bf(fmaxf(ub.z - wb.z, 0.f)) | ((uint32_t)f2bf(fmaxf(ub.w - wb.w, 0.f)) << 16);
    i32x4 v = {(int)p0, (int)p1, (int)p2, (int)p3};
    int kt = k8 >> 3, c = k8 & 7;
    *reinterpret_cast<i32x4*>(h1 + (size_t)row * ND1 + (kt << 6) + (((c ^ (row & 7))) << 3)) = v;
}

// ---------------------------------------------------------------------------
// K3: 256x256 8-phase GEMM — UNCHANGED from R7 (verified 144 µs, conflicts 0).
// ---------------------------------------------------------------------------
#define BARX() do { __builtin_amdgcn_sched_barrier(0); __builtin_amdgcn_s_barrier(); __builtin_amdgcn_sched_barrier(0); } while (0)
#define STG(XG, XL, kt, h) do { \
    const char* _g = (XG) + (size_t)(h) * 131072 + (size_t)(kt) * 128; \
    char* _l = (XL) + (((kt) & 1) << 15) + ((h) << 14) + ldsw; \
    GLL16(_g, _l); \
    GLL16(_g + 65536, _l + 8192); \
} while (0)

__global__ __launch_bounds__(512, 2) void k3_gemm(
        const ushort_t* __restrict__ h1, const ushort_t* __restrict__ W2T,
        float* __restrict__ maxv, float* __restrict__ minv,
        float* __restrict__ psum, float* __restrict__ psq, int g0, int nwg8) {
    __shared__ __align__(16) char lds[131072];
    int b = blockIdx.x;
    int orig = (b & 7) * nwg8 + (b >> 3);
    int mt = orig >> 2, nt = orig & 3;
    int tid = threadIdx.x;
    int w = tid >> 6, l = tid & 63;
    int wm = w >> 2, wn = w & 3;
    int lo = l & 15, lhi = l >> 4;

    int srow = w * 8 + (l >> 3);
    int sbyte = (l & 7) * 16;
    const char* Agb = reinterpret_cast<const char*>(h1) + (size_t)(mt * 256 + srow) * 1024 + sbyte;
    const char* Bgb = reinterpret_cast<const char*>(W2T) + (size_t)(nt * 256 + srow) * 1024 + sbyte;
    char* ldsA = lds;
    char* ldsB = lds + 65536;
    int ldsw = w * 1024;

    int csw0 = ((lhi) ^ (lo & 7)) << 4;
    int csw1 = ((4 + lhi) ^ (lo & 7)) << 4;
    const char* aRB = ldsA + wm * 16384 + lo * 128;
    const char* bRB = ldsB + (wn >> 1) * 16384 + ((wn & 1) * 64 + lo) * 128;

    f32x4 acc[8][4];
    #pragma unroll
    for (int x = 0; x < 8; x++)
        #pragma unroll
        for (int y = 0; y < 4; y++) acc[x][y] = (f32x4){0.f, 0.f, 0.f, 0.f};

    bf16x8 a0[4][2], a1[4][2], bb0[2][2], bb1[2][2];

    auto rdA = [&](bf16x8 (&ar)[4][2], int slot, int qm) {
        #pragma unroll
        for (int f = 0; f < 4; f++) {
            ar[f][0] = *reinterpret_cast<const bf16x8*>(aRB + slot * 32768 + (qm * 64 + f * 16) * 128 + csw0);
            ar[f][1] = *reinterpret_cast<const bf16x8*>(aRB + slot * 32768 + (qm * 64 + f * 16) * 128 + csw1);
        }
    };
    auto rdB = [&](bf16x8 (&br)[2][2], int slot, int qn) {
        #pragma unroll
        for (int f = 0; f < 2; f++) {
            br[f][0] = *reinterpret_cast<const bf16x8*>(bRB + slot * 32768 + (qn * 2 + f) * 2048 + csw0);
            br[f][1] = *reinterpret_cast<const bf16x8*>(bRB + slot * 32768 + (qn * 2 + f) * 2048 + csw1);
        }
    };
    auto mm = [&](int fr0, int fc0, bf16x8 (&ar)[4][2], bf16x8 (&br)[2][2]) {
        __builtin_amdgcn_s_setprio(1);
        #pragma unroll
        for (int kc = 0; kc < 2; kc++)
            #pragma unroll
            for (int f = 0; f < 4; f++)
                #pragma unroll
                for (int c = 0; c < 2; c++)
                    acc[fr0 + f][fc0 + c] = __builtin_amdgcn_mfma_f32_16x16x32_bf16(
                        ar[f][kc], br[c][kc], acc[fr0 + f][fc0 + c], 0, 0, 0);
        __builtin_amdgcn_s_setprio(0);
    };

    STG(Agb, ldsA, 0, 0); STG(Agb, ldsA, 0, 1);
    STG(Bgb, ldsB, 0, 0); STG(Bgb, ldsB, 0, 1);
    STG(Agb, ldsA, 1, 0); STG(Agb, ldsA, 1, 1);
    STG(Bgb, ldsB, 1, 0); STG(Bgb, ldsB, 1, 1);
    asm volatile("s_waitcnt vmcnt(8)" ::: "memory");
    BARX();

    for (int J = 0; J < 4; J++) {
        int kB1 = 2 * J + 1;
        rdA(a0, 0, 0); rdB(bb0, 0, 0);
        if (J > 0) STG(Agb, ldsA, kB1, 0);
        BARX();
        mm(0, 0, a0, bb0);
        BARX();
        rdB(bb1, 0, 1);
        if (J > 0) STG(Agb, ldsA, kB1, 1);
        BARX();
        mm(0, 2, a0, bb1);
        BARX();
        rdA(a1, 0, 1);
        if (J < 3) STG(Bgb, ldsB, kB1 + 1, 0);
        BARX();
        mm(4, 0, a1, bb0);
        BARX();
        if (J < 3) STG(Bgb, ldsB, kB1 + 1, 1);
        BARX();
        mm(4, 2, a1, bb1);
        if (J < 3) asm volatile("s_waitcnt vmcnt(4)" ::: "memory");
        else       asm volatile("s_waitcnt vmcnt(0)" ::: "memory");
        BARX();
        rdA(a0, 1, 0); rdB(bb0, 1, 0);
        if (J < 3) STG(Agb, ldsA, kB1 + 1, 0);
        BARX();
        mm(0, 0, a0, bb0);
        BARX();
        rdB(bb1, 1, 1);
        if (J < 3) STG(Agb, ldsA, kB1 + 1, 1);
        BARX();
        mm(0, 2, a0, bb1);
        BARX();
        rdA(a1, 1, 1);
        if (J < 3) STG(Bgb, ldsB, kB1 + 2, 0);
        BARX();
        mm(4, 0, a1, bb0);
        BARX();
        if (J < 3) STG(Bgb, ldsB, kB1 + 2, 1);
        BARX();
        mm(4, 2, a1, bb1);
        if (J < 3) asm volatile("s_waitcnt vmcnt(4)" ::: "memory");
        BARX();
    }

    int g = g0 + (mt >> 2);
    int qq = mt & 3;
    #pragma unroll
    for (int fc = 0; fc < 4; fc++) {
        int col = nt * 256 + wn * 64 + fc * 16 + lo;
        float sm = 0.f, sq = 0.f;
        float mx[4], mn[4];
        #pragma unroll
        for (int m = 0; m < 4; m++) {
            float vmx = -1e30f, vmn = 1e30f;
            #pragma unroll
            for (int fh = 0; fh < 2; fh++)
                #pragma unroll
                for (int r = 0; r < 4; r++) {
                    float y = acc[2 * m + fh][fc][r];
                    vmx = fmaxf(vmx, y); vmn = fminf(vmn, y);
                    sm += y; sq += y * y;
                }
            vmx = fmaxf(vmx, __shfl_xor(vmx, 16, 64));
            vmx = fmaxf(vmx, __shfl_xor(vmx, 32, 64));
            vmn = fminf(vmn, __shfl_xor(vmn, 16, 64));
            vmn = fminf(vmn, __shfl_xor(vmn, 32, 64));
            mx[m] = vmx; mn[m] = vmn;
        }
        sm += __shfl_xor(sm, 16, 64); sm += __shfl_xor(sm, 32, 64);
        sq += __shfl_xor(sq, 16, 64); sq += __shfl_xor(sq, 32, 64);
        if (lhi == 0) {
            #pragma unroll
            for (int m = 0; m < 4; m++) {
                int i = qq * 8 + wm * 4 + m;
                size_t idx = (size_t)(g * 32 + i) * ND2 + col;
                maxv[idx] = mx[m]; minv[idx] = mn[m];
            }
            atomicAdd(&psum[g * ND2 + col], sm);
            atomicAdd(&psq[g * ND2 + col], sq);
        }
    }
}

// K4: finalize BN2 (+b2 folded analytically) + relu + max-pool select
__global__ void k4_final(const float* __restrict__ maxv, const float* __restrict__ minv,
                         const float* __restrict__ psum, const float* __restrict__ psq,
                         const float* __restrict__ b2, const float* __restrict__ g2,
                         const float* __restrict__ be2, float* __restrict__ out) {
    int g = blockIdx.x >> 2;
    int col = ((blockIdx.x & 3) << 8) + threadIdx.x;
    float b2v = b2[col];
    float s = psum[g * ND2 + col] * (1.f / 1024.f);
    float q = psq[g * ND2 + col] * (1.f / 1024.f);
    float mean = s + b2v;
    float var = q + 2.f * b2v * s + b2v * b2v - mean * mean;
    float A2 = rsqrtf(var + 1e-5f) * g2[col];
    float B2 = be2[col] - mean * A2;
    for (int i = 0; i < 32; i++) {
        size_t idx = (size_t)(g * 32 + i) * ND2 + col;
        float y = ((A2 >= 0.f) ? maxv[idx] : minv[idx]) + b2v;
        out[idx] = fmaxf(y * A2 + B2, 0.f);
    }
}

extern "C" void kernel_launch(void* const* d_in, const int* in_sizes, int n_in,
                              void* d_out, int out_size, void* d_ws, size_t ws_size,
                              hipStream_t stream) {
    (void)in_sizes; (void)n_in; (void)out_size;
    const float* h_states = (const float*)d_in[0];
    const float* end_pos  = (const float*)d_in[2];
    const float* end_spd  = (const float*)d_in[3];
    const float* Ws  = (const float*)d_in[4];
    const float* bs  = (const float*)d_in[5];
    const float* Wv  = (const float*)d_in[6];
    const float* bv  = (const float*)d_in[7];
    const float* W1  = (const float*)d_in[8];
    const float* b1  = (const float*)d_in[9];
    const float* g1  = (const float*)d_in[10];
    const float* be1 = (const float*)d_in[11];
    const float* W2  = (const float*)d_in[12];
    const float* b2  = (const float*)d_in[13];
    const float* g2  = (const float*)d_in[14];
    const float* be2 = (const float*)d_in[15];
    float* ws = (float*)d_ws;
    float* u1   = ws + 2048;                      // fallback only
    float* w1x  = ws + 2099200;                   // fallback only
    ushort_t* W2T = (ushort_t*)(ws + 4196352);    // 524,288 bf16
    float* maxv = ws + 4458496;                   // 4,194,304
    float* minv = ws + 8652800;                   // 4,194,304
    float* psum = ws + 12847104;                  // 131,072
    float* psq  = ws + 12978176;                  // 131,072 (contiguous after psum)
    ushort_t* h1 = (ushort_t*)(ws + 13109248);    // CG*1024*512 bf16
    float* out = (float*)d_out;

    const size_t fixed_f = 13109248ULL;
    const size_t need_full = (fixed_f + 128ULL * 262144ULL) * 4ULL;  // ~187 MB

    if (ws_size >= need_full) {
        // fused path: no u1/w1, no k2b
        hipLaunchKernelGGL(k2_fused, dim3(384), dim3(256), 0, stream,
                           h_states, end_pos, end_spd, W1, g1, be1,
                           Ws, bs, Wv, bv, b1, W2, W2T, h1, psum);
        hipLaunchKernelGGL(k3_gemm, dim3(2048), dim3(512), 0, stream,
                           h1, W2T, maxv, minv, psum, psq, 0, 256);
    } else {
        int CG = 128;
        while (CG > 4 && (fixed_f + (size_t)CG * 262144ULL) * 4ULL > ws_size) CG >>= 1;
        int nch = 128 / CG;
        hipLaunchKernelGGL(k2_all, dim3(384), dim3(256), 0, stream,
                           h_states, end_pos, end_spd, W1, g1, be1,
                           Ws, bs, Wv, bv, b1, W2, W2T, u1, w1x, psum);
        for (int c = 0; c < nch; c++) {
            const float* u1c = u1 + (size_t)c * CG * 32 * ND1;
            const float* w1c = w1x + (size_t)c * CG * 32 * ND1;
            hipLaunchKernelGGL(k2b_h1, dim3(CG * 256), dim3(256), 0, stream, u1c, w1c, h1);
            hipLaunchKernelGGL(k3_gemm, dim3(CG * 16), dim3(512), 0, stream,
                               h1, W2T, maxv, minv, psum, psq, c * CG, CG * 2);
        }
    }
    hipLaunchKernelGGL(k4_final, dim3(512), dim3(256), 0, stream,
                       maxv, minv, psum, psq, b2, g2, be2, out);
}

// Round 11
// 297.784 us; speedup vs baseline: 1.0764x; 1.0764x over previous
//
#include <hip/hip_runtime.h>
#include <cstdint>

typedef unsigned short ushort_t;
typedef __attribute__((ext_vector_type(8))) __bf16 bf16x8;
typedef __attribute__((ext_vector_type(4))) float f32x4;
typedef __attribute__((ext_vector_type(4))) int i32x4;

#define NG 128
#define NP 32
#define NH 64
#define ND1 512
#define ND2 1024

__device__ inline ushort_t f2bf(float f) {
    uint32_t u = __float_as_uint(f);
    uint32_t r = (u + 0x7FFFu + ((u >> 16) & 1u)) >> 16;
    return (ushort_t)r;
}

#define GLL16(gp, lp) __builtin_amdgcn_global_load_lds( \
    (const __attribute__((address_space(1))) unsigned int*)(gp), \
    (__attribute__((address_space(3))) unsigned int*)(lp), 16, 0, 0)

// ---------------------------------------------------------------------------
// K2_fused: grid 384.
//  blocks 0..255 (g,half): zero psum/psq + inline weight-fold + BN1 analytics,
//    then DIRECTLY materialize h1[g*1024 + i*32 + j][ch] = relu(uj[j]-wi[i])
//    as bf16 in the k3 swizzled layout (16B chunk c of each 128B window at
//    c^(row&7)), via a 32KB LDS stage per 64-row i-block.
//    Drain is a LINEAR copy (LDS layout == global layout) -> coalesced stores.
//  blocks 256..383: W2 [512,1024] fp32 -> W2T bf16 [1024][512], same swizzle.
// ---------------------------------------------------------------------------
__global__ void k2_fused(const float* __restrict__ hstates, const float* __restrict__ pos,
                         const float* __restrict__ spd, const float* __restrict__ W1,
                         const float* __restrict__ g1, const float* __restrict__ be1,
                         const float* __restrict__ Ws, const float* __restrict__ bs,
                         const float* __restrict__ Wv, const float* __restrict__ bv,
                         const float* __restrict__ b1, const float* __restrict__ W2,
                         ushort_t* __restrict__ W2T, ushort_t* __restrict__ h1,
                         float* __restrict__ psum) {
    __shared__ float hid_s[32][64];
    __shared__ float pos_s[32][2];
    __shared__ float spd_s[32];
    __shared__ ushort_t tile[64][65];
    __shared__ __align__(16) char stage[32768];
    int b = blockIdx.x, tid = threadIdx.x;
    if (b < 256) {
        // zero psum+psq (contiguous 262144 floats)
        int t0 = b * 256 + tid;
        #pragma unroll
        for (int z = 0; z < 4; z++) psum[t0 + z * 65536] = 0.f;
        int g = b >> 1, half = b & 1;
        int ch = (half << 8) + tid;
        for (int t = tid; t < 2048; t += 256) hid_s[t >> 6][t & 63] = hstates[g * 2048 + t];
        if (tid < 64) pos_s[tid >> 1][tid & 1] = pos[g * 64 + tid];
        if (tid < 32) spd_s[tid] = spd[g * 32 + tid];
        // inline weight fold
        float m0 = 0.f, m1 = 0.f, uu = 0.f, vv = b1[ch];
        for (int e = 0; e < 64; e++) {
            float w1a = W1[e * ND1 + ch];
            float w1c = W1[(128 + e) * ND1 + ch];
            m0 += Ws[e] * w1a;
            m1 += Ws[64 + e] * w1a;
            uu += Wv[e] * w1c;
            vv += bs[e] * w1a + bv[e] * w1c;
        }
        __syncthreads();
        float cj[32], qj[32];
        #pragma unroll
        for (int j = 0; j < 32; j++) {
            qj[j] = pos_s[j][0] * m0 + pos_s[j][1] * m1;
            cj[j] = vv + spd_s[j] * uu;
        }
        for (int h = 0; h < 64; h++) {
            float w = W1[(64 + h) * ND1 + ch];
            #pragma unroll
            for (int j = 0; j < 32; j++) cj[j] += hid_s[j][h] * w;
        }
        float S1 = 0.f, S2 = 0.f, C1 = 0.f, Cq = 0.f, C2 = 0.f;
        #pragma unroll
        for (int j = 0; j < 32; j++) {
            S1 += qj[j]; S2 += qj[j] * qj[j];
            C1 += cj[j]; Cq += cj[j] * qj[j]; C2 += cj[j] * cj[j];
        }
        float mean = C1 * (1.0f / 32.0f);
        float sumsq = 64.f * S2 - 2.f * S1 * S1 + 64.f * Cq - 2.f * S1 * C1 + 32.f * C2;
        float var = sumsq * (1.0f / 1024.0f) - mean * mean;
        float A1 = rsqrtf(var + 1e-5f) * g1[ch];
        float B1 = be1[ch] - mean * A1;
        // uj/wi in registers
        float uj[32], wi[32];
        #pragma unroll
        for (int j = 0; j < 32; j++) {
            uj[j] = (qj[j] + cj[j]) * A1 + B1;
            wi[j] = qj[j] * A1;
        }
        // h1 emission: 16 i-blocks of 64 rows (2 i-values x 32 j)
        int wloc = (ch >> 6) & 3;       // 128B window within this 512B half-row
        int chsw = (ch >> 3) & 7;       // 16B chunk within window
        int chlo = (ch & 7) * 2;        // byte within chunk
        char* sbase = stage + wloc * 128 + chlo;
        const char* hbase = (const char*)0;
        (void)hbase;
        #pragma unroll
        for (int ib = 0; ib < 16; ib++) {
            __syncthreads();            // stage free (prev drain done)
            #pragma unroll
            for (int ii = 0; ii < 2; ii++) {
                float w = wi[ib * 2 + ii];
                #pragma unroll
                for (int j = 0; j < 32; j++) {
                    float v = fmaxf(uj[j] - w, 0.f);
                    *(ushort_t*)(sbase + (ii * 32 + j) * 512 + ((chsw ^ (j & 7)) << 4)) = f2bf(v);
                }
            }
            __syncthreads();
            // drain: LDS layout == global layout -> LINEAR coalesced copy.
            // Each row's 512B half is contiguous in global; a wave covers 2 rows.
            char* gdst0 = (char*)h1 + (size_t)(g * 1024 + ib * 64) * 1024 + half * 512;
            #pragma unroll
            for (int it = 0; it < 8; it++) {
                int c2 = it * 256 + tid;
                int r = c2 >> 5;
                int off = (c2 & 31) << 4;
                *reinterpret_cast<i32x4*>(gdst0 + (size_t)r * 1024 + off) =
                    *reinterpret_cast<const i32x4*>(stage + r * 512 + off);
            }
        }
    } else {
        // W2T transpose with swizzled chunk layout
        int tb = b - 256;
        int kb2 = tb & 7, nb = tb >> 3;
        #pragma unroll
        for (int e = 0; e < 16; e++) {
            int lin = tid + e * 256;
            int k = lin >> 6, n = lin & 63;
            tile[k][n] = f2bf(W2[(kb2 * 64 + k) * ND2 + nb * 64 + n]);
        }
        __syncthreads();
        #pragma unroll
        for (int e = 0; e < 16; e++) {
            int lin = tid + e * 256;
            int kl = lin & 63, nl = lin >> 6;
            int n = nb * 64 + nl, k = kb2 * 64 + kl;
            int idx = n * ND1 + ((k >> 6) << 6) + (((((k >> 3) & 7) ^ (n & 7))) << 3) + (k & 7);
            W2T[idx] = tile[kl][nl];
        }
    }
}

// ---------------------------------------------------------------------------
// Fallback path kernels (ws too small for full h1): identical to R7.
// ---------------------------------------------------------------------------
__global__ void k2_all(const float* __restrict__ hstates, const float* __restrict__ pos,
                       const float* __restrict__ spd, const float* __restrict__ W1,
                       const float* __restrict__ g1, const float* __restrict__ be1,
                       const float* __restrict__ Ws, const float* __restrict__ bs,
                       const float* __restrict__ Wv, const float* __restrict__ bv,
                       const float* __restrict__ b1, const float* __restrict__ W2,
                       ushort_t* __restrict__ W2T,
                       float* __restrict__ u1, float* __restrict__ w1,
                       float* __restrict__ psum) {
    __shared__ float hid_s[32][64];
    __shared__ float pos_s[32][2];
    __shared__ float spd_s[32];
    __shared__ ushort_t tile[64][65];
    int b = blockIdx.x, tid = threadIdx.x;
    if (b < 256) {
        int t0 = b * 256 + tid;
        #pragma unroll
        for (int z = 0; z < 4; z++) psum[t0 + z * 65536] = 0.f;
        int g = b >> 1;
        int ch = ((b & 1) << 8) + tid;
        for (int t = tid; t < 2048; t += 256) hid_s[t >> 6][t & 63] = hstates[g * 2048 + t];
        if (tid < 64) pos_s[tid >> 1][tid & 1] = pos[g * 64 + tid];
        if (tid < 32) spd_s[tid] = spd[g * 32 + tid];
        float m0 = 0.f, m1 = 0.f, uu = 0.f, vv = b1[ch];
        for (int e = 0; e < 64; e++) {
            float w1a = W1[e * ND1 + ch];
            float w1c = W1[(128 + e) * ND1 + ch];
            m0 += Ws[e] * w1a;
            m1 += Ws[64 + e] * w1a;
            uu += Wv[e] * w1c;
            vv += bs[e] * w1a + bv[e] * w1c;
        }
        __syncthreads();
        float cj[32], qj[32];
        #pragma unroll
        for (int j = 0; j < 32; j++) {
            qj[j] = pos_s[j][0] * m0 + pos_s[j][1] * m1;
            cj[j] = vv + spd_s[j] * uu;
        }
        for (int h = 0; h < 64; h++) {
            float w = W1[(64 + h) * ND1 + ch];
            #pragma unroll
            for (int j = 0; j < 32; j++) cj[j] += hid_s[j][h] * w;
        }
        float S1 = 0.f, S2 = 0.f, C1 = 0.f, Cq = 0.f, C2 = 0.f;
        #pragma unroll
        for (int j = 0; j < 32; j++) {
            S1 += qj[j]; S2 += qj[j] * qj[j];
            C1 += cj[j]; Cq += cj[j] * qj[j]; C2 += cj[j] * cj[j];
        }
        float mean = C1 * (1.0f / 32.0f);
        float sumsq = 64.f * S2 - 2.f * S1 * S1 + 64.f * Cq - 2.f * S1 * C1 + 32.f * C2;
        float var = sumsq * (1.0f / 1024.0f) - mean * mean;
        float A1 = rsqrtf(var + 1e-5f) * g1[ch];
        float B1 = be1[ch] - mean * A1;
        #pragma unroll
        for (int j = 0; j < 32; j++) {
            u1[(g * 32 + j) * ND1 + ch] = (qj[j] + cj[j]) * A1 + B1;
            w1[(g * 32 + j) * ND1 + ch] = qj[j] * A1;
        }
    } else {
        int tb = b - 256;
        int kb2 = tb & 7, nb = tb >> 3;
        #pragma unroll
        for (int e = 0; e < 16; e++) {
            int lin = tid + e * 256;
            int k = lin >> 6, n = lin & 63;
            tile[k][n] = f2bf(W2[(kb2 * 64 + k) * ND2 + nb * 64 + n]);
        }
        __syncthreads();
        #pragma unroll
        for (int e = 0; e < 16; e++) {
            int lin = tid + e * 256;
            int kl = lin & 63, nl = lin >> 6;
            int n = nb * 64 + nl, k = kb2 * 64 + kl;
            int idx = n * ND1 + ((k >> 6) << 6) + (((((k >> 3) & 7) ^ (n & 7))) << 3) + (k & 7);
            W2T[idx] = tile[kl][nl];
        }
    }
}

__global__ void k2b_h1(const float* __restrict__ u1c, const float* __restrict__ w1c,
                       ushort_t* __restrict__ h1) {
    int t = blockIdx.x * 256 + threadIdx.x;
    int k8 = t & 63;
    int row = t >> 6;
    int gc = row >> 10, rem = row & 1023;
    int i = rem >> 5, j = rem & 31;
    const float4* pu = reinterpret_cast<const float4*>(u1c + (size_t)(gc * 32 + j) * ND1 + k8 * 8);
    const float4* pw = reinterpret_cast<const float4*>(w1c + (size_t)(gc * 32 + i) * ND1 + k8 * 8);
    float4 ua = pu[0], ub = pu[1], wa = pw[0], wb = pw[1];
    uint32_t p0 = (uint32_t)f2bf(fmaxf(ua.x - wa.x, 0.f)) | ((uint32_t)f2bf(fmaxf(ua.y - wa.y, 0.f)) << 16);
    uint32_t p1 = (uint32_t)f2bf(fmaxf(ua.z - wa.z, 0.f)) | ((uint32_t)f2bf(fmaxf(ua.w - wa.w, 0.f)) << 16);
    uint32_t p2 = (uint32_t)f2bf(fmaxf(ub.x - wb.x, 0.f)) | ((uint32_t)f2bf(fmaxf(ub.y - wb.y, 0.f)) << 16);
    uint32_t p3 = (uint32_t)f2bf(fmaxf(ub.z - wb.z, 0.f)) | ((uint32_t)f2bf(fmaxf(ub.w - wb.w, 0.f)) << 16);
    i32x4 v = {(int)p0, (int)p1, (int)p2, (int)p3};
    int kt = k8 >> 3, c = k8 & 7;
    *reinterpret_cast<i32x4*>(h1 + (size_t)row * ND1 + (kt << 6) + (((c ^ (row & 7))) << 3)) = v;
}

// ---------------------------------------------------------------------------
// K3: 256x256 8-phase GEMM — UNCHANGED (verified 144 µs, conflicts 0).
// ---------------------------------------------------------------------------
#define BARX() do { __builtin_amdgcn_sched_barrier(0); __builtin_amdgcn_s_barrier(); __builtin_amdgcn_sched_barrier(0); } while (0)
#define STG(XG, XL, kt, h) do { \
    const char* _g = (XG) + (size_t)(h) * 131072 + (size_t)(kt) * 128; \
    char* _l = (XL) + (((kt) & 1) << 15) + ((h) << 14) + ldsw; \
    GLL16(_g, _l); \
    GLL16(_g + 65536, _l + 8192); \
} while (0)

__global__ __launch_bounds__(512, 2) void k3_gemm(
        const ushort_t* __restrict__ h1, const ushort_t* __restrict__ W2T,
        float* __restrict__ maxv, float* __restrict__ minv,
        float* __restrict__ psum, float* __restrict__ psq, int g0, int nwg8) {
    __shared__ __align__(16) char lds[131072];
    int b = blockIdx.x;
    int orig = (b & 7) * nwg8 + (b >> 3);
    int mt = orig >> 2, nt = orig & 3;
    int tid = threadIdx.x;
    int w = tid >> 6, l = tid & 63;
    int wm = w >> 2, wn = w & 3;
    int lo = l & 15, lhi = l >> 4;

    int srow = w * 8 + (l >> 3);
    int sbyte = (l & 7) * 16;
    const char* Agb = reinterpret_cast<const char*>(h1) + (size_t)(mt * 256 + srow) * 1024 + sbyte;
    const char* Bgb = reinterpret_cast<const char*>(W2T) + (size_t)(nt * 256 + srow) * 1024 + sbyte;
    char* ldsA = lds;
    char* ldsB = lds + 65536;
    int ldsw = w * 1024;

    int csw0 = ((lhi) ^ (lo & 7)) << 4;
    int csw1 = ((4 + lhi) ^ (lo & 7)) << 4;
    const char* aRB = ldsA + wm * 16384 + lo * 128;
    const char* bRB = ldsB + (wn >> 1) * 16384 + ((wn & 1) * 64 + lo) * 128;

    f32x4 acc[8][4];
    #pragma unroll
    for (int x = 0; x < 8; x++)
        #pragma unroll
        for (int y = 0; y < 4; y++) acc[x][y] = (f32x4){0.f, 0.f, 0.f, 0.f};

    bf16x8 a0[4][2], a1[4][2], bb0[2][2], bb1[2][2];

    auto rdA = [&](bf16x8 (&ar)[4][2], int slot, int qm) {
        #pragma unroll
        for (int f = 0; f < 4; f++) {
            ar[f][0] = *reinterpret_cast<const bf16x8*>(aRB + slot * 32768 + (qm * 64 + f * 16) * 128 + csw0);
            ar[f][1] = *reinterpret_cast<const bf16x8*>(aRB + slot * 32768 + (qm * 64 + f * 16) * 128 + csw1);
        }
    };
    auto rdB = [&](bf16x8 (&br)[2][2], int slot, int qn) {
        #pragma unroll
        for (int f = 0; f < 2; f++) {
            br[f][0] = *reinterpret_cast<const bf16x8*>(bRB + slot * 32768 + (qn * 2 + f) * 2048 + csw0);
            br[f][1] = *reinterpret_cast<const bf16x8*>(bRB + slot * 32768 + (qn * 2 + f) * 2048 + csw1);
        }
    };
    auto mm = [&](int fr0, int fc0, bf16x8 (&ar)[4][2], bf16x8 (&br)[2][2]) {
        __builtin_amdgcn_s_setprio(1);
        #pragma unroll
        for (int kc = 0; kc < 2; kc++)
            #pragma unroll
            for (int f = 0; f < 4; f++)
                #pragma unroll
                for (int c = 0; c < 2; c++)
                    acc[fr0 + f][fc0 + c] = __builtin_amdgcn_mfma_f32_16x16x32_bf16(
                        ar[f][kc], br[c][kc], acc[fr0 + f][fc0 + c], 0, 0, 0);
        __builtin_amdgcn_s_setprio(0);
    };

    STG(Agb, ldsA, 0, 0); STG(Agb, ldsA, 0, 1);
    STG(Bgb, ldsB, 0, 0); STG(Bgb, ldsB, 0, 1);
    STG(Agb, ldsA, 1, 0); STG(Agb, ldsA, 1, 1);
    STG(Bgb, ldsB, 1, 0); STG(Bgb, ldsB, 1, 1);
    asm volatile("s_waitcnt vmcnt(8)" ::: "memory");
    BARX();

    for (int J = 0; J < 4; J++) {
        int kB1 = 2 * J + 1;
        rdA(a0, 0, 0); rdB(bb0, 0, 0);
        if (J > 0) STG(Agb, ldsA, kB1, 0);
        BARX();
        mm(0, 0, a0, bb0);
        BARX();
        rdB(bb1, 0, 1);
        if (J > 0) STG(Agb, ldsA, kB1, 1);
        BARX();
        mm(0, 2, a0, bb1);
        BARX();
        rdA(a1, 0, 1);
        if (J < 3) STG(Bgb, ldsB, kB1 + 1, 0);
        BARX();
        mm(4, 0, a1, bb0);
        BARX();
        if (J < 3) STG(Bgb, ldsB, kB1 + 1, 1);
        BARX();
        mm(4, 2, a1, bb1);
        if (J < 3) asm volatile("s_waitcnt vmcnt(4)" ::: "memory");
        else       asm volatile("s_waitcnt vmcnt(0)" ::: "memory");
        BARX();
        rdA(a0, 1, 0); rdB(bb0, 1, 0);
        if (J < 3) STG(Agb, ldsA, kB1 + 1, 0);
        BARX();
        mm(0, 0, a0, bb0);
        BARX();
        rdB(bb1, 1, 1);
        if (J < 3) STG(Agb, ldsA, kB1 + 1, 1);
        BARX();
        mm(0, 2, a0, bb1);
        BARX();
        rdA(a1, 1, 1);
        if (J < 3) STG(Bgb, ldsB, kB1 + 2, 0);
        BARX();
        mm(4, 0, a1, bb0);
        BARX();
        if (J < 3) STG(Bgb, ldsB, kB1 + 2, 1);
        BARX();
        mm(4, 2, a1, bb1);
        if (J < 3) asm volatile("s_waitcnt vmcnt(4)" ::: "memory");
        BARX();
    }

    int g = g0 + (mt >> 2);
    int qq = mt & 3;
    #pragma unroll
    for (int fc = 0; fc < 4; fc++) {
        int col = nt * 256 + wn * 64 + fc * 16 + lo;
        float sm = 0.f, sq = 0.f;
        float mx[4], mn[4];
        #pragma unroll
        for (int m = 0; m < 4; m++) {
            float vmx = -1e30f, vmn = 1e30f;
            #pragma unroll
            for (int fh = 0; fh < 2; fh++)
                #pragma unroll
                for (int r = 0; r < 4; r++) {
                    float y = acc[2 * m + fh][fc][r];
                    vmx = fmaxf(vmx, y); vmn = fminf(vmn, y);
                    sm += y; sq += y * y;
                }
            vmx = fmaxf(vmx, __shfl_xor(vmx, 16, 64));
            vmx = fmaxf(vmx, __shfl_xor(vmx, 32, 64));
            vmn = fminf(vmn, __shfl_xor(vmn, 16, 64));
            vmn = fminf(vmn, __shfl_xor(vmn, 32, 64));
            mx[m] = vmx; mn[m] = vmn;
        }
        sm += __shfl_xor(sm, 16, 64); sm += __shfl_xor(sm, 32, 64);
        sq += __shfl_xor(sq, 16, 64); sq += __shfl_xor(sq, 32, 64);
        if (lhi == 0) {
            #pragma unroll
            for (int m = 0; m < 4; m++) {
                int i = qq * 8 + wm * 4 + m;
                size_t idx = (size_t)(g * 32 + i) * ND2 + col;
                maxv[idx] = mx[m]; minv[idx] = mn[m];
            }
            atomicAdd(&psum[g * ND2 + col], sm);
            atomicAdd(&psq[g * ND2 + col], sq);
        }
    }
}

// K4: finalize BN2 (+b2 folded analytically) + relu + max-pool select
__global__ void k4_final(const float* __restrict__ maxv, const float* __restrict__ minv,
                         const float* __restrict__ psum, const float* __restrict__ psq,
                         const float* __restrict__ b2, const float* __restrict__ g2,
                         const float* __restrict__ be2, float* __restrict__ out) {
    int g = blockIdx.x >> 2;
    int col = ((blockIdx.x & 3) << 8) + threadIdx.x;
    float b2v = b2[col];
    float s = psum[g * ND2 + col] * (1.f / 1024.f);
    float q = psq[g * ND2 + col] * (1.f / 1024.f);
    float mean = s + b2v;
    float var = q + 2.f * b2v * s + b2v * b2v - mean * mean;
    float A2 = rsqrtf(var + 1e-5f) * g2[col];
    float B2 = be2[col] - mean * A2;
    for (int i = 0; i < 32; i++) {
        size_t idx = (size_t)(g * 32 + i) * ND2 + col;
        float y = ((A2 >= 0.f) ? maxv[idx] : minv[idx]) + b2v;
        out[idx] = fmaxf(y * A2 + B2, 0.f);
    }
}

extern "C" void kernel_launch(void* const* d_in, const int* in_sizes, int n_in,
                              void* d_out, int out_size, void* d_ws, size_t ws_size,
                              hipStream_t stream) {
    (void)in_sizes; (void)n_in; (void)out_size;
    const float* h_states = (const float*)d_in[0];
    const float* end_pos  = (const float*)d_in[2];
    const float* end_spd  = (const float*)d_in[3];
    const float* Ws  = (const float*)d_in[4];
    const float* bs  = (const float*)d_in[5];
    const float* Wv  = (const float*)d_in[6];
    const float* bv  = (const float*)d_in[7];
    const float* W1  = (const float*)d_in[8];
    const float* b1  = (const float*)d_in[9];
    const float* g1  = (const float*)d_in[10];
    const float* be1 = (const float*)d_in[11];
    const float* W2  = (const float*)d_in[12];
    const float* b2  = (const float*)d_in[13];
    const float* g2  = (const float*)d_in[14];
    const float* be2 = (const float*)d_in[15];
    float* ws = (float*)d_ws;
    float* u1   = ws + 2048;                      // fallback only
    float* w1x  = ws + 2099200;                   // fallback only
    ushort_t* W2T = (ushort_t*)(ws + 4196352);    // 524,288 bf16
    float* maxv = ws + 4458496;                   // 4,194,304
    float* minv = ws + 8652800;                   // 4,194,304
    float* psum = ws + 12847104;                  // 131,072
    float* psq  = ws + 12978176;                  // 131,072 (contiguous after psum)
    ushort_t* h1 = (ushort_t*)(ws + 13109248);    // CG*1024*512 bf16
    float* out = (float*)d_out;

    const size_t fixed_f = 13109248ULL;
    const size_t need_full = (fixed_f + 128ULL * 262144ULL) * 4ULL;  // ~187 MB

    if (ws_size >= need_full) {
        // fused path: no u1/w1, no k2b
        hipLaunchKernelGGL(k2_fused, dim3(384), dim3(256), 0, stream,
                           h_states, end_pos, end_spd, W1, g1, be1,
                           Ws, bs, Wv, bv, b1, W2, W2T, h1, psum);
        hipLaunchKernelGGL(k3_gemm, dim3(2048), dim3(512), 0, stream,
                           h1, W2T, maxv, minv, psum, psq, 0, 256);
    } else {
        int CG = 128;
        while (CG > 4 && (fixed_f + (size_t)CG * 262144ULL) * 4ULL > ws_size) CG >>= 1;
        int nch = 128 / CG;
        hipLaunchKernelGGL(k2_all, dim3(384), dim3(256), 0, stream,
                           h_states, end_pos, end_spd, W1, g1, be1,
                           Ws, bs, Wv, bv, b1, W2, W2T, u1, w1x, psum);
        for (int c = 0; c < nch; c++) {
            const float* u1c = u1 + (size_t)c * CG * 32 * ND1;
            const float* w1c = w1x + (size_t)c * CG * 32 * ND1;
            hipLaunchKernelGGL(k2b_h1, dim3(CG * 256), dim3(256), 0, stream, u1c, w1c, h1);
            hipLaunchKernelGGL(k3_gemm, dim3(CG * 16), dim3(512), 0, stream,
                               h1, W2T, maxv, minv, psum, psq, c * CG, CG * 2);
        }
    }
    hipLaunchKernelGGL(k4_final, dim3(512), dim3(256), 0, stream,
                       maxv, minv, psum, psq, b2, g2, be2, out);
}